// Round 7
// baseline (385176.270 us; speedup 1.0000x reference)
//
#include <hip/hip_runtime.h>
#include <hip/hip_bf16.h>

typedef unsigned short u16;

// ---------------- constants ----------------
// B=64, T=512, C=512, H=512, D=80, RF=2, PRE_IN=160, PRE_INNER=256, CONV_CH=32, K=31

__device__ __forceinline__ float b2f(u16 u) {
  return __uint_as_float(((unsigned)u) << 16);
}
__device__ __forceinline__ u16 f2b(float f) {   // RNE f32->bf16
  unsigned u = __float_as_uint(f);
  u += 0x7fffu + ((u >> 16) & 1u);
  return (u16)(u >> 16);
}
// dtype-generic input load / output store (F32: raw f32; else bf16 u16)
template<bool F32>
__device__ __forceinline__ float ldw(const void* p, size_t i) {
  return F32 ? ((const float*)p)[i] : b2f(((const u16*)p)[i]);
}
template<bool F32>
__device__ __forceinline__ void stout(void* p, size_t i, float v) {
  if (F32) ((float*)p)[i] = v; else ((u16*)p)[i] = f2b(v);
}
__device__ __forceinline__ float frcp(float x) { return __builtin_amdgcn_rcpf(x); }
__device__ __forceinline__ float tanh_f(float x) {
  float e = __expf(2.f * x);
  return 1.f - 2.f * frcp(e + 1.f);     // inf-safe
}
__device__ __forceinline__ float sig_f(float x) { return frcp(1.f + __expf(-x)); }

// ---------------- ws layout (float offsets), 9,873,536 floats = 39.5 MB ----------------
constexpr size_t OBAR  = 0;                       // bar[0]=cnt, bar[32]=gen, bar[64]=dtype flag
constexpr size_t OASUM = OBAR  + 128;             // att_sum [b][t]     32768
constexpr size_t ODEC  = OASUM + 32768;           // dec    [b][h]      32768
constexpr size_t OH0   = ODEC  + 32768;           // h0T    [h][b]      32768
constexpr size_t OH1   = OH0   + 32768;           // h1T    [h][b]      32768
constexpr size_t OPO   = OH1   + 32768;           // poT    [n][b]      10240
constexpr size_t OZEND = OPO   + 10240;
constexpr int    ZERO_SPAN_N = (int)OZEND;        // 141440
constexpr size_t OPRV  = OZEND;                   // prev_w [b][t]      32768
constexpr size_t OERG  = OPRV  + 32768;           // erg    [b][t]      32768
constexpr size_t OX1   = OERG  + 32768;           // x1T    [n][b]      16384
constexpr size_t OX2   = OX1   + 16384;           // x2T    [n][b]      32768
constexpr size_t OATTC = OX2   + 32768;           // attcT  [c][b]      32768
constexpr size_t OMM   = OATTC + 32768;           // M[h][32] f32       16384
constexpr size_t OGI0  = OMM   + 16384;           // gi0p [4][1536][64] 393216 (setup alias: encT)
constexpr size_t OGH0  = OGI0  + 393216;          // gh0p               196608
constexpr size_t OGH1  = OGH0  + 196608;          // gh1p               196608
constexpr size_t OGI1  = OGH1  + 196608;          // gi1p               393216
constexpr size_t OPM   = OGI1  + 393216;          // pm bf16 (16.7M u16 = 8388608 slots)
constexpr size_t OTOT  = OPM   + 8388608;

// ---------------- software grid barrier (agent scope) ----------------
__device__ __forceinline__ void gridbar(int* bar) {
  __syncthreads();
  if (threadIdx.x == 0) {
    __threadfence();
    int* cnt = bar;
    int* gen = bar + 32;
    int g = __hip_atomic_load(gen, __ATOMIC_RELAXED, __HIP_MEMORY_SCOPE_AGENT);
    int a = __hip_atomic_fetch_add(cnt, 1, __ATOMIC_ACQ_REL, __HIP_MEMORY_SCOPE_AGENT);
    if (a == 255) {
      __hip_atomic_store(cnt, 0, __ATOMIC_RELAXED, __HIP_MEMORY_SCOPE_AGENT);
      __hip_atomic_store(gen, g + 1, __ATOMIC_RELEASE, __HIP_MEMORY_SCOPE_AGENT);
    } else {
      while (__hip_atomic_load(gen, __ATOMIC_ACQUIRE, __HIP_MEMORY_SCOPE_AGENT) == g)
        __builtin_amdgcn_s_sleep(2);
    }
    __threadfence();
  }
  __syncthreads();
}

// ---------------- setup kernels ----------------
__global__ void k_zero(float* p, int n) {
  for (int i = blockIdx.x * 256 + threadIdx.x; i < n; i += gridDim.x * 256) p[i] = 0.f;
}
// dtype detector: probe pn_w1. bf16 data -> even-index u16s have sane exponent
// fields; f32 data -> even u16s are mantissa low-halves (uniform garbage).
__global__ void k_detect(int* flag, const u16* probe) {
  if (blockIdx.x != 0 || threadIdx.x != 0) return;
  int sane = 0;
  for (int i = 0; i < 256; i += 2) {
    u16 u = probe[i];
    int e = (u >> 7) & 0xFF;
    if (u == 0 || (e >= 97 && e <= 140)) ++sane;
  }
  *flag = (sane < 96) ? 1 : 0;   // 1 => inputs are raw f32
}
__global__ void k_prevw(float* prevw, const int* dlen) {
  int b = blockIdx.x;
  int len = dlen[b] >> 1;
  float inv = 1.f / (float)len;
  for (int i = threadIdx.x; i < 512; i += 256)
    prevw[b * 512 + i] = (i < len) ? inv : 0.f;
}
// att_enc_w [h][c] -> dst [c][h] f32
template<bool F32>
__global__ void k_cvtT512(const int* flag, float* dst, const void* src) {
  if (*flag != (F32 ? 1 : 0)) return;
  for (int i = blockIdx.x * 256 + threadIdx.x; i < 262144; i += gridDim.x * 256) {
    int c = i >> 9, h = i & 511;
    dst[i] = ldw<F32>(src, (size_t)h * 512 + c);
  }
}
// M[h][k] = sum_c loc_w[h][c] * conv_w[c][0][k]
template<bool F32>
__global__ void k_mmat(const int* flag, float* M, const void* locw, const void* convw) {
  if (*flag != (F32 ? 1 : 0)) return;
  int i = blockIdx.x * 256 + threadIdx.x;
  if (i >= 16384) return;
  int h = i >> 5, k = i & 31;
  float acc = 0.f;
  if (k < 31) {
    for (int c = 0; c < 32; ++c)
      acc = fmaf(ldw<F32>(locw, h * 32 + c), ldw<F32>(convw, c * 31 + k), acc);
  }
  M[i] = acc;
}
// pm[b][t][h] = enc[b][t][:] @ att_enc_w[h][:] + b[h]  (stored bf16)
template<bool F32>
__global__ __launch_bounds__(256) void k_pm(const int* flag, u16* pm, const void* enc,
                                            const float* encwT, const void* encb) {
  if (*flag != (F32 ? 1 : 0)) return;
  __shared__ float encf[16 * 512];
  int row0 = blockIdx.x * 16;
  int tid = threadIdx.x;
  for (int i = tid; i < 16 * 512; i += 256) {
    int r = i >> 9, c = i & 511;
    encf[i] = ldw<F32>(enc, (size_t)(row0 + r) * 512 + c);
  }
  __syncthreads();
  float a0[16], a1[16];
  float bb0 = ldw<F32>(encb, tid), bb1 = ldw<F32>(encb, tid + 256);
#pragma unroll
  for (int r = 0; r < 16; ++r) { a0[r] = bb0; a1[r] = bb1; }
  for (int c = 0; c < 512; ++c) {
    float w0 = encwT[c * 512 + tid];
    float w1 = encwT[c * 512 + 256 + tid];
#pragma unroll
    for (int r = 0; r < 16; ++r) {
      float a = encf[r * 512 + c];
      a0[r] = fmaf(w0, a, a0[r]);
      a1[r] = fmaf(w1, a, a1[r]);
    }
  }
#pragma unroll
  for (int r = 0; r < 16; ++r) {
    pm[(size_t)(row0 + r) * 512 + tid]       = f2b(a0[r]);
    pm[(size_t)(row0 + r) * 512 + 256 + tid] = f2b(a1[r]);
  }
}

// ---------------- main persistent kernel ----------------
struct KP {
  const void* __restrict__ enc;
  const int* __restrict__ dlen;
  const u16* __restrict__ pm;          // internal bf16
  const void* __restrict__ wih0; const void* __restrict__ whh0;
  const void* __restrict__ wih1; const void* __restrict__ whh1;
  const void* __restrict__ adec; const void* __restrict__ outw;
  const void* __restrict__ pnw2; const void* __restrict__ pnw1;
  const void* __restrict__ pnb1; const void* __restrict__ pnb2;
  const void* __restrict__ bih0; const void* __restrict__ bhh0;
  const void* __restrict__ bih1; const void* __restrict__ bhh1;
  const void* __restrict__ outb; const void* __restrict__ vw;
  const float* __restrict__ Mg;
  int* __restrict__ bar;
  float* __restrict__ asum; float* __restrict__ dec;
  float* __restrict__ h0T;  float* __restrict__ h1T;  float* __restrict__ poT;
  float* __restrict__ prevw; float* __restrict__ erg;
  float* __restrict__ x1T;  float* __restrict__ x2T;  float* __restrict__ attcT;
  float* __restrict__ gi0p; float* __restrict__ gh0p;
  float* __restrict__ gh1p; float* __restrict__ gi1p;
  void* __restrict__ out;              // out_o at elem 0; out_a at elem 5242880
};

template<bool F32>
__global__ __launch_bounds__(256, 1) void k_loop(KP p) {
  if (*(const volatile int*)(p.bar + 64) != (F32 ? 1 : 0)) return;  // wrong-dtype variant exits
  __shared__ u16  M_u[32 * 512];
  __shared__ float dec_s[512];
  __shared__ float v_s[512];
  __shared__ float wq[160];
  __shared__ float sm[512];
  __shared__ float red[8];

  const int wg = blockIdx.x, tid = threadIdx.x;
  const int lane = tid & 63;
  const int wv = __builtin_amdgcn_readfirstlane(tid >> 6);
  const int wflat = wg * 4 + wv;
  const int b_att = wg >> 2, q = wg & 3, t0 = q * 128;
  const int trow = tid >> 6, hcol = tid & 63;

  for (int i = tid; i < 32 * 512; i += 256) {
    int k = i >> 9, h = i & 511;
    M_u[i] = f2b(p.Mg[h * 32 + k]);
  }
  for (int i = tid; i < 512; i += 256) v_s[i] = ldw<F32>(p.vw, i);
  __syncthreads();

  for (int t = 0; t < 512; ++t) {
    // ===== S1: attention energies (+ prenet-1) =====
    if (wg < 64) {
      int n = wg * 4 + wv;
      float a0 = 0.f, a1 = 0.f;
      for (int k = 0; k < 160; k += 2) {
        a0 = fmaf(ldw<F32>(p.pnw1, n * 160 + k),     p.poT[k * 64 + lane],       a0);
        a1 = fmaf(ldw<F32>(p.pnw1, n * 160 + k + 1), p.poT[(k + 1) * 64 + lane], a1);
      }
      float a = a0 + a1 + ldw<F32>(p.pnb1, n);
      p.x1T[n * 64 + lane] = fmaxf(a, 0.f);
    }
    if (tid < 158) {
      int g = t0 - 15 + tid;
      wq[tid] = (g >= 0 && g < 512) ? p.prevw[b_att * 512 + g] : 0.f;
    }
    for (int i = tid; i < 512; i += 256) dec_s[i] = p.dec[b_att * 512 + i];
    __syncthreads();
    {
      float wreg[62];
#pragma unroll
      for (int i = 0; i < 62; ++i) wreg[i] = wq[trow * 32 + i];
      float acc[32];
#pragma unroll
      for (int s = 0; s < 32; ++s) acc[s] = 0.f;
      const u16* pmb = p.pm + ((size_t)(b_att * 512 + t0 + trow * 32)) * 512;
      for (int j = 0; j < 8; ++j) {
        int hj = hcol + 64 * j;
        float Mreg[31];
#pragma unroll
        for (int k = 0; k < 31; ++k) Mreg[k] = b2f(M_u[k * 512 + hj]);
        float dj = dec_s[hj], vj = v_s[hj];
#pragma unroll
        for (int s = 0; s < 32; ++s) {
          float u = dj;
#pragma unroll
          for (int k = 0; k < 31; ++k) u = fmaf(Mreg[k], wreg[s + k], u);
          u += b2f(pmb[s * 512 + hj]);
          acc[s] = fmaf(vj, tanh_f(u), acc[s]);
        }
      }
#pragma unroll
      for (int s = 0; s < 32; ++s) {
        float v = acc[s];
#pragma unroll
        for (int off = 32; off; off >>= 1) v += __shfl_xor(v, off, 64);
        if (hcol == 0) sm[trow * 32 + s] = v;
      }
      __syncthreads();
      if (tid < 128) p.erg[b_att * 512 + t0 + tid] = sm[tid];
    }
    gridbar(p.bar);

    // ===== S2: softmax/out_a | att_c | prenet-2 =====
    if (wg < 64) {
      int b = wg;
      int len = p.dlen[b] >> 1;
      float e0 = p.erg[b * 512 + tid], e1 = p.erg[b * 512 + 256 + tid];
      bool v0 = tid < len, v1 = (256 + tid) < len;
      float mx = fmaxf(v0 ? e0 : -1e30f, v1 ? e1 : -1e30f);
#pragma unroll
      for (int off = 32; off; off >>= 1) mx = fmaxf(mx, __shfl_xor(mx, off, 64));
      if (lane == 0) red[wv] = mx;
      __syncthreads();
      mx = fmaxf(fmaxf(red[0], red[1]), fmaxf(red[2], red[3]));
      float x0 = v0 ? __expf(e0 - mx) : 0.f;
      float x1 = v1 ? __expf(e1 - mx) : 0.f;
      float s = x0 + x1;
#pragma unroll
      for (int off = 32; off; off >>= 1) s += __shfl_xor(s, off, 64);
      if (lane == 0) red[4 + wv] = s;
      __syncthreads();
      s = red[4] + red[5] + red[6] + red[7];
      float inv = 1.f / s;
      float w0 = x0 * inv, w1 = x1 * inv;
      stout<F32>(p.out, 5242880 + (size_t)b * 262144 + (size_t)tid * 512 + t, w0);
      stout<F32>(p.out, 5242880 + (size_t)b * 262144 + (size_t)(tid + 256) * 512 + t, w1);
      float s0 = p.asum[b * 512 + tid] + w0;
      float s1 = p.asum[b * 512 + 256 + tid] + w1;
      p.asum[b * 512 + tid] = s0;          p.prevw[b * 512 + tid] = s0;
      p.asum[b * 512 + 256 + tid] = s1;    p.prevw[b * 512 + 256 + tid] = s1;
    } else if (wg < 192) {
      int idx = wg - 64, b = idx >> 1, half = idx & 1;
      int len = p.dlen[b] >> 1;
      float e0 = p.erg[b * 512 + tid], e1 = p.erg[b * 512 + 256 + tid];
      bool v0 = tid < len, v1 = (256 + tid) < len;
      float mx = fmaxf(v0 ? e0 : -1e30f, v1 ? e1 : -1e30f);
#pragma unroll
      for (int off = 32; off; off >>= 1) mx = fmaxf(mx, __shfl_xor(mx, off, 64));
      if (lane == 0) red[wv] = mx;
      __syncthreads();
      mx = fmaxf(fmaxf(red[0], red[1]), fmaxf(red[2], red[3]));
      float x0 = v0 ? __expf(e0 - mx) : 0.f;
      float x1 = v1 ? __expf(e1 - mx) : 0.f;
      float s = x0 + x1;
#pragma unroll
      for (int off = 32; off; off >>= 1) s += __shfl_xor(s, off, 64);
      if (lane == 0) red[4 + wv] = s;
      __syncthreads();
      s = red[4] + red[5] + red[6] + red[7];
      float inv = 1.f / s;
      sm[tid] = x0 * inv; sm[256 + tid] = x1 * inv;
      __syncthreads();
      int c = half * 256 + tid;
      size_t eb = (size_t)b * 262144 + c;
      float a0 = 0.f, a1 = 0.f, a2 = 0.f, a3 = 0.f;
      for (int tau = 0; tau < 512; tau += 4) {
        a0 = fmaf(sm[tau],     ldw<F32>(p.enc, eb + (size_t)tau * 512),       a0);
        a1 = fmaf(sm[tau + 1], ldw<F32>(p.enc, eb + (size_t)(tau + 1) * 512), a1);
        a2 = fmaf(sm[tau + 2], ldw<F32>(p.enc, eb + (size_t)(tau + 2) * 512), a2);
        a3 = fmaf(sm[tau + 3], ldw<F32>(p.enc, eb + (size_t)(tau + 3) * 512), a3);
      }
      p.attcT[c * 64 + b] = (a0 + a1) + (a2 + a3);
    } else {
      int idx = wg - 192;
      int n0 = (idx * 4 + wv) * 2;
      float a0 = 0.f, a1 = 0.f, c0 = 0.f, c1 = 0.f;
      for (int k = 0; k < 256; k += 2) {
        float x0 = p.x1T[k * 64 + lane], x1 = p.x1T[(k + 1) * 64 + lane];
        a0 = fmaf(ldw<F32>(p.pnw2, n0 * 256 + k),           x0, a0);
        a1 = fmaf(ldw<F32>(p.pnw2, n0 * 256 + k + 1),       x1, a1);
        c0 = fmaf(ldw<F32>(p.pnw2, (n0 + 1) * 256 + k),     x0, c0);
        c1 = fmaf(ldw<F32>(p.pnw2, (n0 + 1) * 256 + k + 1), x1, c1);
      }
      float xa = a0 + a1 + ldw<F32>(p.pnb2, n0), xb = c0 + c1 + ldw<F32>(p.pnb2, n0 + 1);
      p.x2T[n0 * 64 + lane]       = fmaxf(xa, 0.f);
      p.x2T[(n0 + 1) * 64 + lane] = fmaxf(xb, 0.f);
    }
    gridbar(p.bar);

    // ===== S3: gi0 | gh0 | gh1 =====
    {
      int w = wflat;
      if (w < 512) {
        int kpart = w & 3, n0 = (w >> 2) * 12;
        const float* AT = (kpart < 2) ? p.x2T : p.attcT;
        int k0 = (kpart & 1) * 256;
        size_t wofs = (size_t)(kpart >> 1) * 512;
        float acc[12];
#pragma unroll
        for (int i = 0; i < 12; ++i) acc[i] = 0.f;
        for (int k = k0; k < k0 + 256; ++k) {
          float a = AT[k * 64 + lane];
#pragma unroll
          for (int i = 0; i < 12; ++i)
            acc[i] = fmaf(ldw<F32>(p.wih0, (size_t)(n0 + i) * 1024 + wofs + k), a, acc[i]);
        }
#pragma unroll
        for (int i = 0; i < 12; ++i)
          p.gi0p[((size_t)kpart * 1536 + n0 + i) * 64 + lane] = acc[i];
      } else if (w < 768) {
        int u = w - 512; int kpart = u & 1, n0 = (u >> 1) * 12, k0 = kpart * 256;
        float acc[12];
#pragma unroll
        for (int i = 0; i < 12; ++i) acc[i] = 0.f;
        for (int k = k0; k < k0 + 256; ++k) {
          float a = p.h0T[k * 64 + lane];
#pragma unroll
          for (int i = 0; i < 12; ++i)
            acc[i] = fmaf(ldw<F32>(p.whh0, (size_t)(n0 + i) * 512 + k), a, acc[i]);
        }
#pragma unroll
        for (int i = 0; i < 12; ++i)
          p.gh0p[((size_t)kpart * 1536 + n0 + i) * 64 + lane] = acc[i];
      } else {
        int u = w - 768; int kpart = u & 1, n0 = (u >> 1) * 12, k0 = kpart * 256;
        float acc[12];
#pragma unroll
        for (int i = 0; i < 12; ++i) acc[i] = 0.f;
        for (int k = k0; k < k0 + 256; ++k) {
          float a = p.h1T[k * 64 + lane];
#pragma unroll
          for (int i = 0; i < 12; ++i)
            acc[i] = fmaf(ldw<F32>(p.whh1, (size_t)(n0 + i) * 512 + k), a, acc[i]);
        }
#pragma unroll
        for (int i = 0; i < 12; ++i)
          p.gh1p[((size_t)kpart * 1536 + n0 + i) * 64 + lane] = acc[i];
      }
    }
    gridbar(p.bar);

    // ===== S4: GRU0 combine -> h0' =====
    if (wg < 128) {
      int e = wg * 256 + tid;
      int h = e >> 6, b = e & 63;
      float ir = p.gi0p[h * 64 + b] + p.gi0p[(1536 + h) * 64 + b]
               + p.gi0p[(3072 + h) * 64 + b] + p.gi0p[(4608 + h) * 64 + b] + ldw<F32>(p.bih0, h);
      float iz = p.gi0p[(512 + h) * 64 + b] + p.gi0p[(2048 + h) * 64 + b]
               + p.gi0p[(3584 + h) * 64 + b] + p.gi0p[(5120 + h) * 64 + b] + ldw<F32>(p.bih0, 512 + h);
      float in = p.gi0p[(1024 + h) * 64 + b] + p.gi0p[(2560 + h) * 64 + b]
               + p.gi0p[(4096 + h) * 64 + b] + p.gi0p[(5632 + h) * 64 + b] + ldw<F32>(p.bih0, 1024 + h);
      float hr = p.gh0p[h * 64 + b] + p.gh0p[(1536 + h) * 64 + b] + ldw<F32>(p.bhh0, h);
      float hz = p.gh0p[(512 + h) * 64 + b] + p.gh0p[(2048 + h) * 64 + b] + ldw<F32>(p.bhh0, 512 + h);
      float hn = p.gh0p[(1024 + h) * 64 + b] + p.gh0p[(2560 + h) * 64 + b] + ldw<F32>(p.bhh0, 1024 + h);
      float r = sig_f(ir + hr), z = sig_f(iz + hz);
      float nn = tanh_f(in + r * hn);
      float ho = p.h0T[h * 64 + b];
      p.h0T[h * 64 + b] = (1.f - z) * nn + z * ho;
    }
    gridbar(p.bar);

    // ===== S5: gi1 | dec_next =====
    {
      int w = wflat;
      if (w < 512) {
        int kpart = w & 3, n0 = (w >> 2) * 12, k0 = kpart * 128;
        float acc[12];
#pragma unroll
        for (int i = 0; i < 12; ++i) acc[i] = 0.f;
        for (int k = k0; k < k0 + 128; ++k) {
          float a = p.h0T[k * 64 + lane];
#pragma unroll
          for (int i = 0; i < 12; ++i)
            acc[i] = fmaf(ldw<F32>(p.wih1, (size_t)(n0 + i) * 512 + k), a, acc[i]);
        }
#pragma unroll
        for (int i = 0; i < 12; ++i)
          p.gi1p[((size_t)kpart * 1536 + n0 + i) * 64 + lane] = acc[i];
      } else if (w < 768) {
        int u = w - 512, n0 = u * 2;
        float a0 = 0.f, a1 = 0.f, c0 = 0.f, c1 = 0.f;
        for (int k = 0; k < 512; k += 2) {
          float x0 = p.h0T[k * 64 + lane], x1 = p.h0T[(k + 1) * 64 + lane];
          a0 = fmaf(ldw<F32>(p.adec, (size_t)n0 * 512 + k),           x0, a0);
          a1 = fmaf(ldw<F32>(p.adec, (size_t)n0 * 512 + k + 1),       x1, a1);
          c0 = fmaf(ldw<F32>(p.adec, (size_t)(n0 + 1) * 512 + k),     x0, c0);
          c1 = fmaf(ldw<F32>(p.adec, (size_t)(n0 + 1) * 512 + k + 1), x1, c1);
        }
        p.dec[lane * 512 + n0]     = a0 + a1;
        p.dec[lane * 512 + n0 + 1] = c0 + c1;
      }
    }
    gridbar(p.bar);

    // ===== S6: GRU1 combine -> h1' =====
    if (wg < 128) {
      int e = wg * 256 + tid;
      int h = e >> 6, b = e & 63;
      float ir = p.gi1p[h * 64 + b] + p.gi1p[(1536 + h) * 64 + b]
               + p.gi1p[(3072 + h) * 64 + b] + p.gi1p[(4608 + h) * 64 + b] + ldw<F32>(p.bih1, h);
      float iz = p.gi1p[(512 + h) * 64 + b] + p.gi1p[(2048 + h) * 64 + b]
               + p.gi1p[(3584 + h) * 64 + b] + p.gi1p[(5120 + h) * 64 + b] + ldw<F32>(p.bih1, 512 + h);
      float in = p.gi1p[(1024 + h) * 64 + b] + p.gi1p[(2560 + h) * 64 + b]
               + p.gi1p[(4096 + h) * 64 + b] + p.gi1p[(5632 + h) * 64 + b] + ldw<F32>(p.bih1, 1024 + h);
      float hr = p.gh1p[h * 64 + b] + p.gh1p[(1536 + h) * 64 + b] + ldw<F32>(p.bhh1, h);
      float hz = p.gh1p[(512 + h) * 64 + b] + p.gh1p[(2048 + h) * 64 + b] + ldw<F32>(p.bhh1, 512 + h);
      float hn = p.gh1p[(1024 + h) * 64 + b] + p.gh1p[(2560 + h) * 64 + b] + ldw<F32>(p.bhh1, 1024 + h);
      float r = sig_f(ir + hr), z = sig_f(iz + hz);
      float nn = tanh_f(in + r * hn);
      float ho = p.h1T[h * 64 + b];
      p.h1T[h * 64 + b] = (1.f - z) * nn + z * ho;
    }
    gridbar(p.bar);

    // ===== S7: out = Wout @ [h1' ; att_c] + b =====
    if (wflat < 160) {
      int n = wflat;
      size_t wr = (size_t)n * 1024;
      float a0 = 0.f, a1 = 0.f, a2 = 0.f, a3 = 0.f;
      for (int k = 0; k < 512; k += 2) {
        a0 = fmaf(ldw<F32>(p.outw, wr + k),           p.h1T[k * 64 + lane],         a0);
        a1 = fmaf(ldw<F32>(p.outw, wr + k + 1),       p.h1T[(k + 1) * 64 + lane],   a1);
        a2 = fmaf(ldw<F32>(p.outw, wr + 512 + k),     p.attcT[k * 64 + lane],       a2);
        a3 = fmaf(ldw<F32>(p.outw, wr + 512 + k + 1), p.attcT[(k + 1) * 64 + lane], a3);
      }
      float acc = (a0 + a1) + (a2 + a3) + ldw<F32>(p.outb, n);
      p.poT[n * 64 + lane] = acc;
      stout<F32>(p.out, (size_t)lane * 81920 + (size_t)(n >> 1) * 1024 + t * 2 + (n & 1), acc);
    }
    gridbar(p.bar);
  }
}

// ---------------- host launcher ----------------
extern "C" void kernel_launch(void* const* d_in, const int* in_sizes, int n_in,
                              void* d_out, int out_size, void* d_ws, size_t ws_size,
                              hipStream_t stream) {
  (void)in_sizes; (void)n_in; (void)out_size; (void)ws_size;
  const void* enc   = d_in[0];
  const int*  dlen  = (const int*)d_in[1];
  const void* pnw1  = d_in[2];
  const void* pnb1  = d_in[3];
  const void* pnw2  = d_in[4];
  const void* pnb2  = d_in[5];
  const void* aencw = d_in[6];
  const void* aencb = d_in[7];
  const void* adecw = d_in[8];
  const void* aconv = d_in[9];
  const void* alocw = d_in[10];
  const void* avw   = d_in[11];
  // d_in[12] = att_v_b: softmax-invariant -> unused
  const void* wih0  = d_in[13];
  const void* whh0  = d_in[14];
  const void* bih0  = d_in[15];
  const void* bhh0  = d_in[16];
  const void* wih1  = d_in[17];
  const void* whh1  = d_in[18];
  const void* bih1  = d_in[19];
  const void* bhh1  = d_in[20];
  const void* outw  = d_in[21];
  const void* outb  = d_in[22];

  float* W = (float*)d_ws;
  int* flag = (int*)(W + OBAR) + 64;
  dim3 blk(256);

  k_zero<<<256, blk, 0, stream>>>(W + OBAR, ZERO_SPAN_N);
  k_detect<<<1, blk, 0, stream>>>(flag, (const u16*)pnw1);
  k_prevw<<<64, blk, 0, stream>>>(W + OPRV, dlen);
  // dual-dtype setup (wrong variant self-disables via flag)
  k_mmat<false><<<64, blk, 0, stream>>>(flag, W + OMM, alocw, aconv);
  k_mmat<true ><<<64, blk, 0, stream>>>(flag, W + OMM, alocw, aconv);
  k_cvtT512<false><<<512, blk, 0, stream>>>(flag, W + OGI0, aencw);
  k_cvtT512<true ><<<512, blk, 0, stream>>>(flag, W + OGI0, aencw);
  k_pm<false><<<2048, blk, 0, stream>>>(flag, (u16*)(W + OPM), enc, W + OGI0, aencb);
  k_pm<true ><<<2048, blk, 0, stream>>>(flag, (u16*)(W + OPM), enc, W + OGI0, aencb);

  KP kp;
  kp.enc = enc; kp.dlen = dlen;
  kp.pm = (const u16*)(W + OPM);
  kp.wih0 = wih0; kp.whh0 = whh0;
  kp.wih1 = wih1; kp.whh1 = whh1;
  kp.adec = adecw; kp.outw = outw;
  kp.pnw2 = pnw2; kp.pnw1 = pnw1;
  kp.pnb1 = pnb1; kp.pnb2 = pnb2;
  kp.bih0 = bih0; kp.bhh0 = bhh0;
  kp.bih1 = bih1; kp.bhh1 = bhh1;
  kp.outb = outb; kp.vw = avw;
  kp.Mg = W + OMM;
  kp.bar = (int*)(W + OBAR);
  kp.asum = W + OASUM; kp.dec = W + ODEC;
  kp.h0T = W + OH0; kp.h1T = W + OH1; kp.poT = W + OPO;
  kp.prevw = W + OPRV; kp.erg = W + OERG;
  kp.x1T = W + OX1; kp.x2T = W + OX2; kp.attcT = W + OATTC;
  kp.gi0p = W + OGI0; kp.gh0p = W + OGH0;
  kp.gh1p = W + OGH1; kp.gi1p = W + OGI1;
  kp.out = d_out;

  // both variants launched; the wrong-dtype one exits before touching the barrier
  k_loop<false><<<dim3(256), blk, 0, stream>>>(kp);
  k_loop<true ><<<dim3(256), blk, 0, stream>>>(kp);
}